// Round 1
// baseline (547.602 us; speedup 1.0000x reference)
//
#include <hip/hip_runtime.h>
#include <hip/hip_bf16.h>

#define N_PTS (4096 * 192)
#define STRIDE 136   // bf16 elems per LDS act row (128 + 8 pad -> 2-way-free bank spread)
#define TM 128       // points per block

typedef __bf16 bf16x8 __attribute__((ext_vector_type(8)));
typedef float  f32x4  __attribute__((ext_vector_type(4)));

// ws element-offset layout (bf16):
//   w1T @ 0      (128x128, [n][k])
//   w2T @ 16384  (first 128 rows of w2, transposed -> [n][k])
//   w3T @ 32768
//   wfT @ 49152
//   wrT @ 65536  (64x128, [n][k])
__global__ void prep_kernel(const float* __restrict__ w1, const float* __restrict__ w2,
                            const float* __restrict__ w3, const float* __restrict__ wf,
                            const float* __restrict__ wr, __bf16* __restrict__ ws) {
  int i = blockIdx.x * blockDim.x + threadIdx.x;
  if (i < 16384) {
    int n = i >> 7, k = i & 127;
    ws[i] = (__bf16)w1[k * 128 + n];
  } else if (i < 32768) {
    int j = i - 16384; int n = j >> 7, k = j & 127;
    ws[i] = (__bf16)w2[k * 128 + n];
  } else if (i < 49152) {
    int j = i - 32768; int n = j >> 7, k = j & 127;
    ws[i] = (__bf16)w3[k * 128 + n];
  } else if (i < 65536) {
    int j = i - 49152; int n = j >> 7, k = j & 127;
    ws[i] = (__bf16)wf[k * 128 + n];
  } else if (i < 73728) {
    int j = i - 65536; int n = j >> 7, k = j & 127;   // n < 64
    ws[i] = (__bf16)wr[k * 64 + n];
  }
}

// Accumulate act(128xK=128, LDS bf16) @ wT(N, [n][k] bf16 global) into acc.
// Wave computes cols [nbase, nbase + NT*16).
template <int NT>
__device__ __forceinline__ void gemm128(const __bf16* __restrict__ actb,
                                        const __bf16* __restrict__ wT,
                                        f32x4 (&acc)[8][NT], int nbase, int l16, int quad) {
#pragma unroll
  for (int kk = 0; kk < 4; ++kk) {
    bf16x8 a[8];
#pragma unroll
    for (int mt = 0; mt < 8; ++mt)
      a[mt] = *(const bf16x8*)(actb + (mt * 16 + l16) * STRIDE + kk * 32 + quad * 8);
#pragma unroll
    for (int nt = 0; nt < NT; ++nt) {
      bf16x8 b = *(const bf16x8*)(wT + (size_t)(nbase + nt * 16 + l16) * 128 + kk * 32 + quad * 8);
#pragma unroll
      for (int mt = 0; mt < 8; ++mt)
        acc[mt][nt] = __builtin_amdgcn_mfma_f32_16x16x32_bf16(a[mt], b, acc[mt][nt], 0, 0, 0);
    }
  }
}

__global__ __launch_bounds__(256) void nerf_kernel(
    const float* __restrict__ x,
    const float* __restrict__ w0, const float* __restrict__ b0,
    const float* __restrict__ b1,
    const float* __restrict__ w2, const float* __restrict__ b2,
    const float* __restrict__ b3,
    const float* __restrict__ wd, const float* __restrict__ bd,
    const float* __restrict__ bfv,
    const float* __restrict__ wr, const float* __restrict__ br,
    const float* __restrict__ wo, const float* __restrict__ bo,
    const __bf16* __restrict__ ws,
    float* __restrict__ out) {
  __shared__ __bf16 act[TM * STRIDE];   // 34,816 B
  __shared__ float  pos[TM * 4];        // 2,048 B
  __shared__ float  vdir[TM * 4];       // 2,048 B

  const int tid  = threadIdx.x;
  const int wv   = tid >> 6;
  const int lane = tid & 63;
  const int quad = lane >> 4;
  const int l16  = lane & 15;
  const int p0   = blockIdx.x * TM;

  // ---- stage x tile: pos/viewdir fp32 in LDS ----
  for (int i = tid; i < TM * 6; i += 256) {
    int p = i / 6, c = i % 6;
    float v = x[(size_t)(p0 + p) * 6 + c];
    if (c < 3) pos[p * 4 + c] = v;
    else       vdir[p * 4 + (c - 3)] = v;
  }
  __syncthreads();

  // ---- layer 0: h0 = relu(pos @ w0 + b0), K=3 on VALU ----
  {
    int m  = tid >> 1;
    int nb = (tid & 1) * 64;
    float px = pos[m * 4], py = pos[m * 4 + 1], pz = pos[m * 4 + 2];
#pragma unroll 8
    for (int n = nb; n < nb + 64; ++n) {
      float v = b0[n] + px * w0[n] + py * w0[128 + n] + pz * w0[256 + n];
      act[m * STRIDE + n] = (__bf16)fmaxf(v, 0.f);
    }
  }
  __syncthreads();

  // ---- layer 1: h1 = relu(h0 @ w1 + b1) ----
  {
    f32x4 acc[8][2];
    int nbase = wv * 32;
#pragma unroll
    for (int nt = 0; nt < 2; ++nt) {
      float b = b1[nbase + nt * 16 + l16];
#pragma unroll
      for (int mt = 0; mt < 8; ++mt) { f32x4 bb = {b, b, b, b}; acc[mt][nt] = bb; }
    }
    gemm128<2>(act, ws + 0, acc, nbase, l16, quad);
    __syncthreads();
#pragma unroll
    for (int nt = 0; nt < 2; ++nt) {
      int col = nbase + nt * 16 + l16;
#pragma unroll
      for (int mt = 0; mt < 8; ++mt)
#pragma unroll
        for (int r = 0; r < 4; ++r) {
          int m = mt * 16 + quad * 4 + r;
          act[m * STRIDE + col] = (__bf16)fmaxf(acc[mt][nt][r], 0.f);
        }
    }
    __syncthreads();
  }

  // ---- layer 2: h2 = relu([h1, pos] @ w2 + b2) = relu(h1 @ w2[:128] + pos @ w2[128:] + b2) ----
  {
    f32x4 acc[8][2];
    int nbase = wv * 32;
#pragma unroll
    for (int nt = 0; nt < 2; ++nt) {
      float b = b2[nbase + nt * 16 + l16];
#pragma unroll
      for (int mt = 0; mt < 8; ++mt) { f32x4 bb = {b, b, b, b}; acc[mt][nt] = bb; }
    }
    gemm128<2>(act, ws + 16384, acc, nbase, l16, quad);
    __syncthreads();
#pragma unroll
    for (int nt = 0; nt < 2; ++nt) {
      int col = nbase + nt * 16 + l16;
      float t0 = w2[128 * 128 + col], t1 = w2[129 * 128 + col], t2 = w2[130 * 128 + col];
#pragma unroll
      for (int mt = 0; mt < 8; ++mt)
#pragma unroll
        for (int r = 0; r < 4; ++r) {
          int m = mt * 16 + quad * 4 + r;
          float v = acc[mt][nt][r] + pos[m * 4] * t0 + pos[m * 4 + 1] * t1 + pos[m * 4 + 2] * t2;
          act[m * STRIDE + col] = (__bf16)fmaxf(v, 0.f);
        }
    }
    __syncthreads();
  }

  // ---- layer 3: h3 = relu(h2 @ w3 + b3) ----
  {
    f32x4 acc[8][2];
    int nbase = wv * 32;
#pragma unroll
    for (int nt = 0; nt < 2; ++nt) {
      float b = b3[nbase + nt * 16 + l16];
#pragma unroll
      for (int mt = 0; mt < 8; ++mt) { f32x4 bb = {b, b, b, b}; acc[mt][nt] = bb; }
    }
    gemm128<2>(act, ws + 32768, acc, nbase, l16, quad);
    __syncthreads();
#pragma unroll
    for (int nt = 0; nt < 2; ++nt) {
      int col = nbase + nt * 16 + l16;
#pragma unroll
      for (int mt = 0; mt < 8; ++mt)
#pragma unroll
        for (int r = 0; r < 4; ++r) {
          int m = mt * 16 + quad * 4 + r;
          act[m * STRIDE + col] = (__bf16)fmaxf(acc[mt][nt][r], 0.f);
        }
    }
    __syncthreads();
  }

  // ---- density = relu(h3 @ wd + bd), K=128 dot on VALU (2 threads/point) ----
  {
    int p = tid >> 1, half = tid & 1;
    float s = 0.f;
    const __bf16* hrow = act + p * STRIDE + half * 64;
    const float*  wdp  = wd + half * 64;
#pragma unroll 16
    for (int k = 0; k < 64; ++k) s += (float)hrow[k] * wdp[k];
    s += __shfl_xor(s, 1, 64);
    if (half == 0) out[(size_t)3 * N_PTS + p0 + p] = fmaxf(s + bd[0], 0.f);
  }
  // (no barrier needed: density only READS act; next gemm also only reads)

  // ---- features = relu(h3 @ wf + bf) ----
  {
    f32x4 acc[8][2];
    int nbase = wv * 32;
#pragma unroll
    for (int nt = 0; nt < 2; ++nt) {
      float b = bfv[nbase + nt * 16 + l16];
#pragma unroll
      for (int mt = 0; mt < 8; ++mt) { f32x4 bb = {b, b, b, b}; acc[mt][nt] = bb; }
    }
    gemm128<2>(act, ws + 49152, acc, nbase, l16, quad);
    __syncthreads();
#pragma unroll
    for (int nt = 0; nt < 2; ++nt) {
      int col = nbase + nt * 16 + l16;
#pragma unroll
      for (int mt = 0; mt < 8; ++mt)
#pragma unroll
        for (int r = 0; r < 4; ++r) {
          int m = mt * 16 + quad * 4 + r;
          act[m * STRIDE + col] = (__bf16)fmaxf(acc[mt][nt][r], 0.f);
        }
    }
    __syncthreads();
  }

  // ---- r = relu([features, vdir] @ wr + br), N=64 ----
  {
    f32x4 acc[8][1];
    int nbase = wv * 16;
    float b = br[nbase + l16];
#pragma unroll
    for (int mt = 0; mt < 8; ++mt) { f32x4 bb = {b, b, b, b}; acc[mt][0] = bb; }
    gemm128<1>(act, ws + 65536, acc, nbase, l16, quad);
    __syncthreads();
    int col = nbase + l16;
    float t0 = wr[128 * 64 + col], t1 = wr[129 * 64 + col], t2 = wr[130 * 64 + col];
#pragma unroll
    for (int mt = 0; mt < 8; ++mt)
#pragma unroll
      for (int r = 0; r < 4; ++r) {
        int m = mt * 16 + quad * 4 + r;
        float v = acc[mt][0][r] + vdir[m * 4] * t0 + vdir[m * 4 + 1] * t1 + vdir[m * 4 + 2] * t2;
        act[m * STRIDE + col] = (__bf16)fmaxf(v, 0.f);
      }
    __syncthreads();
  }

  // ---- rgb = sigmoid(r @ wo + bo), K=64, N=3 on VALU (2 threads/point) ----
  {
    int p = tid >> 1, half = tid & 1;
    float s0 = 0.f, s1 = 0.f, s2 = 0.f;
    const __bf16* rrow = act + p * STRIDE + half * 32;
#pragma unroll 8
    for (int k = 0; k < 32; ++k) {
      float rv = (float)rrow[k];
      int kg = half * 32 + k;
      s0 += rv * wo[kg * 3 + 0];
      s1 += rv * wo[kg * 3 + 1];
      s2 += rv * wo[kg * 3 + 2];
    }
    s0 += __shfl_xor(s0, 1, 64);
    s1 += __shfl_xor(s1, 1, 64);
    s2 += __shfl_xor(s2, 1, 64);
    if (half == 0) {
      size_t o = (size_t)(p0 + p) * 3;
      out[o + 0] = 1.f / (1.f + expf(-(s0 + bo[0])));
      out[o + 1] = 1.f / (1.f + expf(-(s1 + bo[1])));
      out[o + 2] = 1.f / (1.f + expf(-(s2 + bo[2])));
    }
  }
}

extern "C" void kernel_launch(void* const* d_in, const int* in_sizes, int n_in,
                              void* d_out, int out_size, void* d_ws, size_t ws_size,
                              hipStream_t stream) {
  const float* x  = (const float*)d_in[0];
  const float* w0 = (const float*)d_in[1];
  const float* b0 = (const float*)d_in[2];
  const float* w1 = (const float*)d_in[3];
  const float* b1 = (const float*)d_in[4];
  const float* w2 = (const float*)d_in[5];
  const float* b2 = (const float*)d_in[6];
  const float* w3 = (const float*)d_in[7];
  const float* b3 = (const float*)d_in[8];
  const float* wd = (const float*)d_in[9];
  const float* bd = (const float*)d_in[10];
  const float* wf = (const float*)d_in[11];
  const float* bfv= (const float*)d_in[12];
  const float* wr = (const float*)d_in[13];
  const float* br = (const float*)d_in[14];
  const float* wo = (const float*)d_in[15];
  const float* bo = (const float*)d_in[16];
  __bf16* ws = (__bf16*)d_ws;
  float* out = (float*)d_out;

  prep_kernel<<<288, 256, 0, stream>>>(w1, w2, w3, wf, wr, ws);
  nerf_kernel<<<N_PTS / TM, 256, 0, stream>>>(x, w0, b0, b1, w2, b2, b3, wd, bd,
                                              bfv, wr, br, wo, bo, ws, out);
}

// Round 2
// 357.532 us; speedup vs baseline: 1.5316x; 1.5316x over previous
//
#include <hip/hip_runtime.h>
#include <hip/hip_bf16.h>

#define N_PTS (4096 * 192)
#define STRIDE 136   // bf16 elems per LDS act row
#define TM 128       // points per block

typedef __bf16 bf16x8 __attribute__((ext_vector_type(8)));
typedef __bf16 bf16x4 __attribute__((ext_vector_type(4)));
typedef float  f32x4  __attribute__((ext_vector_type(4)));

// ws element-offset layout (bf16), all [n][k] transposed:
//   w1T @ 0, w2T @ 16384 (rows 0..127), w3T @ 32768, wfT @ 49152, wrT @ 65536 (64x128)
__global__ void prep_kernel(const float* __restrict__ w1, const float* __restrict__ w2,
                            const float* __restrict__ w3, const float* __restrict__ wf,
                            const float* __restrict__ wr, __bf16* __restrict__ ws) {
  int i = blockIdx.x * blockDim.x + threadIdx.x;
  if (i < 16384) {
    int n = i >> 7, k = i & 127;
    ws[i] = (__bf16)w1[k * 128 + n];
  } else if (i < 32768) {
    int j = i - 16384; int n = j >> 7, k = j & 127;
    ws[i] = (__bf16)w2[k * 128 + n];
  } else if (i < 49152) {
    int j = i - 32768; int n = j >> 7, k = j & 127;
    ws[i] = (__bf16)w3[k * 128 + n];
  } else if (i < 65536) {
    int j = i - 49152; int n = j >> 7, k = j & 127;
    ws[i] = (__bf16)wf[k * 128 + n];
  } else if (i < 73728) {
    int j = i - 65536; int n = j >> 7, k = j & 127;   // n < 64
    ws[i] = (__bf16)wr[k * 64 + n];
  }
}

// acc[pt][nt] += wT-tile (as A: M=features) x act-tile (as B: N=points).
// D per lane: point = pt*16 + l16, features = nbase + nt*16 + quad*4 + {0..3}.
template <int NT>
__device__ __forceinline__ void gemmW(const __bf16* __restrict__ actb,
                                      const __bf16* __restrict__ wT,
                                      f32x4 (&acc)[8][NT], int nbase, int l16, int quad) {
#pragma unroll
  for (int kk = 0; kk < 4; ++kk) {
    bf16x8 w[NT];
#pragma unroll
    for (int nt = 0; nt < NT; ++nt)
      w[nt] = *(const bf16x8*)(wT + (size_t)(nbase + nt * 16 + l16) * 128 + kk * 32 + quad * 8);
#pragma unroll
    for (int pt = 0; pt < 8; ++pt) {
      bf16x8 a = *(const bf16x8*)(actb + (pt * 16 + l16) * STRIDE + kk * 32 + quad * 8);
#pragma unroll
      for (int nt = 0; nt < NT; ++nt)
        acc[pt][nt] = __builtin_amdgcn_mfma_f32_16x16x32_bf16(w[nt], a, acc[pt][nt], 0, 0, 0);
    }
  }
}

__global__ __launch_bounds__(256, 4) void nerf_kernel(
    const float* __restrict__ x,
    const float* __restrict__ w0, const float* __restrict__ b0,
    const float* __restrict__ b1,
    const float* __restrict__ w2, const float* __restrict__ b2,
    const float* __restrict__ b3,
    const float* __restrict__ wd, const float* __restrict__ bd,
    const float* __restrict__ bfv,
    const float* __restrict__ wr, const float* __restrict__ br,
    const float* __restrict__ wo, const float* __restrict__ bo,
    const __bf16* __restrict__ ws,
    float* __restrict__ out) {
  __shared__ __bf16 act[TM * STRIDE];   // 34,816 B
  __shared__ float  pos[TM * 4];        // 2,048 B
  __shared__ float  vdir[TM * 4];       // 2,048 B

  const int tid  = threadIdx.x;
  const int wv   = tid >> 6;
  const int lane = tid & 63;
  const int quad = lane >> 4;
  const int l16  = lane & 15;
  const int p0   = blockIdx.x * TM;

  // ---- stage x tile ----
  for (int i = tid; i < TM * 6; i += 256) {
    int p = i / 6, c = i % 6;
    float v = x[(size_t)(p0 + p) * 6 + c];
    if (c < 3) pos[p * 4 + c] = v;
    else       vdir[p * 4 + (c - 3)] = v;
  }
  __syncthreads();

  // ---- layer 0: h0 = relu(pos @ w0 + b0), K=3 on VALU, packed b64 stores ----
  {
    int m  = tid >> 1;
    int nb = (tid & 1) * 64;
    float px = pos[m * 4], py = pos[m * 4 + 1], pz = pos[m * 4 + 2];
#pragma unroll 4
    for (int n = nb; n < nb + 64; n += 4) {
      f32x4 b0v = *(const f32x4*)(b0 + n);
      f32x4 w0x = *(const f32x4*)(w0 + n);
      f32x4 w0y = *(const f32x4*)(w0 + 128 + n);
      f32x4 w0z = *(const f32x4*)(w0 + 256 + n);
      f32x4 v = b0v + px * w0x + py * w0y + pz * w0z;
      bf16x4 p;
#pragma unroll
      for (int r = 0; r < 4; ++r) p[r] = (__bf16)fmaxf(v[r], 0.f);
      *(bf16x4*)(act + m * STRIDE + n) = p;
    }
  }
  __syncthreads();

  // ---- layer 1: h1 = relu(h0 @ w1 + b1) ----
  {
    f32x4 acc[8][2];
    int nbase = wv * 32;
    f32x4 bia0 = *(const f32x4*)(b1 + nbase + quad * 4);
    f32x4 bia1 = *(const f32x4*)(b1 + nbase + 16 + quad * 4);
#pragma unroll
    for (int pt = 0; pt < 8; ++pt) { acc[pt][0] = bia0; acc[pt][1] = bia1; }
    gemmW<2>(act, ws + 0, acc, nbase, l16, quad);
    __syncthreads();
#pragma unroll
    for (int nt = 0; nt < 2; ++nt) {
      int nc = nbase + nt * 16 + quad * 4;
#pragma unroll
      for (int pt = 0; pt < 8; ++pt) {
        int m = pt * 16 + l16;
        f32x4 v = acc[pt][nt];
        bf16x4 p;
#pragma unroll
        for (int r = 0; r < 4; ++r) p[r] = (__bf16)fmaxf(v[r], 0.f);
        *(bf16x4*)(act + m * STRIDE + nc) = p;
      }
    }
    __syncthreads();
  }

  // ---- layer 2: h2 = relu(h1 @ w2[:128] + pos @ w2[128:] + b2) ----
  {
    f32x4 acc[8][2];
    int nbase = wv * 32;
    f32x4 bia0 = *(const f32x4*)(b2 + nbase + quad * 4);
    f32x4 bia1 = *(const f32x4*)(b2 + nbase + 16 + quad * 4);
#pragma unroll
    for (int pt = 0; pt < 8; ++pt) { acc[pt][0] = bia0; acc[pt][1] = bia1; }
    gemmW<2>(act, ws + 16384, acc, nbase, l16, quad);
    f32x4 t0[2], t1[2], t2[2];
#pragma unroll
    for (int nt = 0; nt < 2; ++nt) {
      int nc = nbase + nt * 16 + quad * 4;
      t0[nt] = *(const f32x4*)(w2 + 128 * 128 + nc);
      t1[nt] = *(const f32x4*)(w2 + 129 * 128 + nc);
      t2[nt] = *(const f32x4*)(w2 + 130 * 128 + nc);
    }
    __syncthreads();
#pragma unroll
    for (int pt = 0; pt < 8; ++pt) {
      int m = pt * 16 + l16;
      float px = pos[m * 4], py = pos[m * 4 + 1], pz = pos[m * 4 + 2];
#pragma unroll
      for (int nt = 0; nt < 2; ++nt) {
        int nc = nbase + nt * 16 + quad * 4;
        f32x4 v = acc[pt][nt] + px * t0[nt] + py * t1[nt] + pz * t2[nt];
        bf16x4 p;
#pragma unroll
        for (int r = 0; r < 4; ++r) p[r] = (__bf16)fmaxf(v[r], 0.f);
        *(bf16x4*)(act + m * STRIDE + nc) = p;
      }
    }
    __syncthreads();
  }

  // ---- layer 3: h3 = relu(h2 @ w3 + b3) ----
  {
    f32x4 acc[8][2];
    int nbase = wv * 32;
    f32x4 bia0 = *(const f32x4*)(b3 + nbase + quad * 4);
    f32x4 bia1 = *(const f32x4*)(b3 + nbase + 16 + quad * 4);
#pragma unroll
    for (int pt = 0; pt < 8; ++pt) { acc[pt][0] = bia0; acc[pt][1] = bia1; }
    gemmW<2>(act, ws + 32768, acc, nbase, l16, quad);
    __syncthreads();
#pragma unroll
    for (int nt = 0; nt < 2; ++nt) {
      int nc = nbase + nt * 16 + quad * 4;
#pragma unroll
      for (int pt = 0; pt < 8; ++pt) {
        int m = pt * 16 + l16;
        f32x4 v = acc[pt][nt];
        bf16x4 p;
#pragma unroll
        for (int r = 0; r < 4; ++r) p[r] = (__bf16)fmaxf(v[r], 0.f);
        *(bf16x4*)(act + m * STRIDE + nc) = p;
      }
    }
    __syncthreads();
  }

  // ---- density = relu(h3 @ wd + bd), vectorized LDS reads ----
  {
    int p = tid >> 1, half = tid & 1;
    const __bf16* hrow = act + p * STRIDE + half * 64;
    const float*  wdp  = wd + half * 64;
    float s = 0.f;
#pragma unroll
    for (int c = 0; c < 8; ++c) {
      bf16x8 h = *(const bf16x8*)(hrow + c * 8);
      f32x4 wa = *(const f32x4*)(wdp + c * 8);
      f32x4 wb = *(const f32x4*)(wdp + c * 8 + 4);
      s += (float)h[0] * wa[0] + (float)h[1] * wa[1] + (float)h[2] * wa[2] + (float)h[3] * wa[3];
      s += (float)h[4] * wb[0] + (float)h[5] * wb[1] + (float)h[6] * wb[2] + (float)h[7] * wb[3];
    }
    s += __shfl_xor(s, 1, 64);
    if (half == 0) out[(size_t)3 * N_PTS + p0 + p] = fmaxf(s + bd[0], 0.f);
  }
  // (no barrier: density only reads act; features gemm also only reads)

  // ---- features = relu(h3 @ wf + bf) ----
  {
    f32x4 acc[8][2];
    int nbase = wv * 32;
    f32x4 bia0 = *(const f32x4*)(bfv + nbase + quad * 4);
    f32x4 bia1 = *(const f32x4*)(bfv + nbase + 16 + quad * 4);
#pragma unroll
    for (int pt = 0; pt < 8; ++pt) { acc[pt][0] = bia0; acc[pt][1] = bia1; }
    gemmW<2>(act, ws + 49152, acc, nbase, l16, quad);
    __syncthreads();
#pragma unroll
    for (int nt = 0; nt < 2; ++nt) {
      int nc = nbase + nt * 16 + quad * 4;
#pragma unroll
      for (int pt = 0; pt < 8; ++pt) {
        int m = pt * 16 + l16;
        f32x4 v = acc[pt][nt];
        bf16x4 p;
#pragma unroll
        for (int r = 0; r < 4; ++r) p[r] = (__bf16)fmaxf(v[r], 0.f);
        *(bf16x4*)(act + m * STRIDE + nc) = p;
      }
    }
    __syncthreads();
  }

  // ---- r = relu([features, vdir] @ wr + br), N=64 ----
  {
    f32x4 acc[8][1];
    int nbase = wv * 16;
    f32x4 bia0 = *(const f32x4*)(br + nbase + quad * 4);
#pragma unroll
    for (int pt = 0; pt < 8; ++pt) acc[pt][0] = bia0;
    gemmW<1>(act, ws + 65536, acc, nbase, l16, quad);
    int nc = nbase + quad * 4;
    f32x4 t0 = *(const f32x4*)(wr + 128 * 64 + nc);
    f32x4 t1 = *(const f32x4*)(wr + 129 * 64 + nc);
    f32x4 t2 = *(const f32x4*)(wr + 130 * 64 + nc);
    __syncthreads();
#pragma unroll
    for (int pt = 0; pt < 8; ++pt) {
      int m = pt * 16 + l16;
      float vx = vdir[m * 4], vy = vdir[m * 4 + 1], vz = vdir[m * 4 + 2];
      f32x4 v = acc[pt][0] + vx * t0 + vy * t1 + vz * t2;
      bf16x4 p;
#pragma unroll
      for (int r = 0; r < 4; ++r) p[r] = (__bf16)fmaxf(v[r], 0.f);
      *(bf16x4*)(act + m * STRIDE + nc) = p;
    }
    __syncthreads();
  }

  // ---- rgb = sigmoid(r @ wo + bo), vectorized LDS reads ----
  {
    int p = tid >> 1, half = tid & 1;
    const __bf16* rrow = act + p * STRIDE + half * 32;
    float s0 = 0.f, s1 = 0.f, s2 = 0.f;
#pragma unroll
    for (int c = 0; c < 4; ++c) {
      bf16x8 h = *(const bf16x8*)(rrow + c * 8);
#pragma unroll
      for (int j = 0; j < 8; ++j) {
        int kg = half * 32 + c * 8 + j;
        float rv = (float)h[j];
        s0 += rv * wo[kg * 3 + 0];
        s1 += rv * wo[kg * 3 + 1];
        s2 += rv * wo[kg * 3 + 2];
      }
    }
    s0 += __shfl_xor(s0, 1, 64);
    s1 += __shfl_xor(s1, 1, 64);
    s2 += __shfl_xor(s2, 1, 64);
    if (half == 0) {
      size_t o = (size_t)(p0 + p) * 3;
      out[o + 0] = 1.f / (1.f + expf(-(s0 + bo[0])));
      out[o + 1] = 1.f / (1.f + expf(-(s1 + bo[1])));
      out[o + 2] = 1.f / (1.f + expf(-(s2 + bo[2])));
    }
  }
}

extern "C" void kernel_launch(void* const* d_in, const int* in_sizes, int n_in,
                              void* d_out, int out_size, void* d_ws, size_t ws_size,
                              hipStream_t stream) {
  const float* x  = (const float*)d_in[0];
  const float* w0 = (const float*)d_in[1];
  const float* b0 = (const float*)d_in[2];
  const float* w1 = (const float*)d_in[3];
  const float* b1 = (const float*)d_in[4];
  const float* w2 = (const float*)d_in[5];
  const float* b2 = (const float*)d_in[6];
  const float* w3 = (const float*)d_in[7];
  const float* b3 = (const float*)d_in[8];
  const float* wd = (const float*)d_in[9];
  const float* bd = (const float*)d_in[10];
  const float* wf = (const float*)d_in[11];
  const float* bfv= (const float*)d_in[12];
  const float* wr = (const float*)d_in[13];
  const float* br = (const float*)d_in[14];
  const float* wo = (const float*)d_in[15];
  const float* bo = (const float*)d_in[16];
  __bf16* ws = (__bf16*)d_ws;
  float* out = (float*)d_out;

  prep_kernel<<<288, 256, 0, stream>>>(w1, w2, w3, wf, wr, ws);
  nerf_kernel<<<N_PTS / TM, 256, 0, stream>>>(x, w0, b0, b1, w2, b2, b3, wd, bd,
                                              bfv, wr, br, wo, bo, ws, out);
}

// Round 3
// 281.537 us; speedup vs baseline: 1.9450x; 1.2699x over previous
//
#include <hip/hip_runtime.h>
#include <hip/hip_bf16.h>

#define N_PTS (4096 * 192)
#define STRIDE 136     // bf16 elems per LDS act row (16B-aligned rows, 2-way bank class)
#define TM 128         // points per block
#define PB_STRIDE 24   // posb row stride (48B: 16B-aligned, 2-way bank class)

typedef __bf16 bf16x8 __attribute__((ext_vector_type(8)));
typedef __bf16 bf16x4 __attribute__((ext_vector_type(4)));
typedef float  f32x4  __attribute__((ext_vector_type(4)));
typedef float  f32x2  __attribute__((ext_vector_type(2)));

// ws layout (bf16 element offsets), all weight tiles transposed to [n][k]:
#define W1T 0          // 128x128
#define W2T 16384      // 128x128 (rows 0..127 of w2)
#define W3T 32768      // 128x128
#define WFT 49152      // 128x128
#define WRT 65536      // 64x128
#define W0E 73728      // 128x16  fixup: k0-2 w0_hi, k3-5 w0_hi(dup), k6-8 w0_lo
#define W2E 75776      // 128x16  same pattern from w2 rows 128-130
#define WRE 77824      // 64x16   fixup: k9-11 wr_hi(vdir rows), k12-14 wr_hi(dup)
#define WSF 78848      // float region: woT[3][64]

__global__ void prep_kernel(const float* __restrict__ w0, const float* __restrict__ w1,
                            const float* __restrict__ w2, const float* __restrict__ w3,
                            const float* __restrict__ wf, const float* __restrict__ wr,
                            const float* __restrict__ wo, __bf16* __restrict__ ws) {
  int i = blockIdx.x * 256 + threadIdx.x;
  if (i < 16384) { int n = i >> 7, k = i & 127; ws[i] = (__bf16)w1[k * 128 + n]; }
  else if (i < 32768) { int j = i - 16384, n = j >> 7, k = j & 127; ws[i] = (__bf16)w2[k * 128 + n]; }
  else if (i < 49152) { int j = i - 32768, n = j >> 7, k = j & 127; ws[i] = (__bf16)w3[k * 128 + n]; }
  else if (i < 65536) { int j = i - 49152, n = j >> 7, k = j & 127; ws[i] = (__bf16)wf[k * 128 + n]; }
  else if (i < 73728) { int j = i - 65536, n = j >> 7, k = j & 127; ws[i] = (__bf16)wr[k * 64 + n]; }
  else if (i < 75776) {
    int j = i - 73728, f = j >> 4, k = j & 15; float v = 0.f;
    if (k < 3)      v = w0[k * 128 + f];
    else if (k < 6) v = w0[(k - 3) * 128 + f];
    else if (k < 9) { float w = w0[(k - 6) * 128 + f]; v = w - (float)(__bf16)w; }
    ws[i] = (__bf16)v;
  }
  else if (i < 77824) {
    int j = i - 75776, f = j >> 4, k = j & 15; float v = 0.f;
    if (k < 3)      v = w2[(128 + k) * 128 + f];
    else if (k < 6) v = w2[(128 + k - 3) * 128 + f];
    else if (k < 9) { float w = w2[(128 + k - 6) * 128 + f]; v = w - (float)(__bf16)w; }
    ws[i] = (__bf16)v;
  }
  else if (i < 78848) {
    int j = i - 77824, n = j >> 4, k = j & 15; float v = 0.f;
    if (k >= 9 && k < 15) v = wr[(128 + ((k - 9) % 3)) * 64 + n];
    ws[i] = (__bf16)v;
  }
  else if (i < 79040) {
    int g = i - 78848, c = g >> 6, kg = g & 63;
    float* wsf = (float*)(ws + WSF);
    wsf[g] = wo[kg * 3 + c];
  }
}

// acc[pt][nt] += wT-tile (A: M=features) x act-tile (B: N=points), K=128.
template <int NT>
__device__ __forceinline__ void gemmW(const __bf16* __restrict__ actb,
                                      const __bf16* __restrict__ wT,
                                      f32x4 (&acc)[8][NT], int nbase, int l16, int quad) {
#pragma unroll
  for (int kk = 0; kk < 4; ++kk) {
    bf16x8 w[NT];
#pragma unroll
    for (int nt = 0; nt < NT; ++nt)
      w[nt] = *(const bf16x8*)(wT + (size_t)(nbase + nt * 16 + l16) * 128 + kk * 32 + quad * 8);
#pragma unroll
    for (int pt = 0; pt < 8; ++pt) {
      bf16x8 a = *(const bf16x8*)(actb + (pt * 16 + l16) * STRIDE + kk * 32 + quad * 8);
#pragma unroll
      for (int nt = 0; nt < NT; ++nt)
        acc[pt][nt] = __builtin_amdgcn_mfma_f32_16x16x32_bf16(w[nt], a, acc[pt][nt], 0, 0, 0);
    }
  }
}

// One K=32 MFMA block against posb (k0-15 meaningful, quads 2-3 feed zeros).
template <int NT>
__device__ __forceinline__ void gemmFix(const __bf16* __restrict__ posb,
                                        const __bf16* __restrict__ wext,
                                        f32x4 (&acc)[8][NT], int nbase, int l16, int quad) {
  bf16x8 z;
#pragma unroll
  for (int i = 0; i < 8; ++i) z[i] = (__bf16)0.f;
  bf16x8 w[NT];
#pragma unroll
  for (int nt = 0; nt < NT; ++nt) w[nt] = z;
  if (quad < 2) {
#pragma unroll
    for (int nt = 0; nt < NT; ++nt)
      w[nt] = *(const bf16x8*)(wext + (size_t)(nbase + nt * 16 + l16) * 16 + quad * 8);
  }
#pragma unroll
  for (int pt = 0; pt < 8; ++pt) {
    bf16x8 b = z;
    if (quad < 2) b = *(const bf16x8*)(posb + (pt * 16 + l16) * PB_STRIDE + quad * 8);
#pragma unroll
    for (int nt = 0; nt < NT; ++nt)
      acc[pt][nt] = __builtin_amdgcn_mfma_f32_16x16x32_bf16(w[nt], b, acc[pt][nt], 0, 0, 0);
  }
}

__device__ __forceinline__ void store_relu(f32x4 v, __bf16* dst) {
  bf16x4 p;
#pragma unroll
  for (int r = 0; r < 4; ++r) p[r] = (__bf16)fmaxf(v[r], 0.f);
  *(bf16x4*)dst = p;
}

__global__ __launch_bounds__(256, 4) void nerf_kernel(
    const float* __restrict__ x,
    const float* __restrict__ b0, const float* __restrict__ b1,
    const float* __restrict__ b2, const float* __restrict__ b3,
    const float* __restrict__ wd, const float* __restrict__ bd,
    const float* __restrict__ bfv, const float* __restrict__ br,
    const float* __restrict__ bo,
    const __bf16* __restrict__ ws,
    float* __restrict__ out) {
  __shared__ __bf16 act[TM * STRIDE];        // 34,816 B
  __shared__ __bf16 posb[TM * PB_STRIDE];    //  6,144 B  (total 40,960 -> 4 blocks/CU)

  const int tid  = threadIdx.x;
  const int wv   = tid >> 6;
  const int lane = tid & 63;
  const int quad = lane >> 4;
  const int l16  = lane & 15;
  const int p0   = blockIdx.x * TM;

  // ---- stage posb: hi/lo-split pos (k0-2 hi, k3-5 lo, k6-8 hi dup) + vdir (k9-11 hi, k12-14 lo), k15=0
  if (tid < TM) {
    const float* xp = x + (size_t)(p0 + tid) * 6;
    f32x2 a = *(const f32x2*)xp;
    f32x2 b = *(const f32x2*)(xp + 2);
    f32x2 c = *(const f32x2*)(xp + 4);
    float px = a[0], py = a[1], pz = b[0], vx = b[1], vy = c[0], vz = c[1];
    __bf16 phx = (__bf16)px, phy = (__bf16)py, phz = (__bf16)pz;
    __bf16 vhx = (__bf16)vx, vhy = (__bf16)vy, vhz = (__bf16)vz;
    __bf16 plx = (__bf16)(px - (float)phx), ply = (__bf16)(py - (float)phy), plz = (__bf16)(pz - (float)phz);
    __bf16 vlx = (__bf16)(vx - (float)vhx), vly = (__bf16)(vy - (float)vhy), vlz = (__bf16)(vz - (float)vhz);
    bf16x8 r0, r1;
    r0[0] = phx; r0[1] = phy; r0[2] = phz; r0[3] = plx; r0[4] = ply; r0[5] = plz; r0[6] = phx; r0[7] = phy;
    r1[0] = phz; r1[1] = vhx; r1[2] = vhy; r1[3] = vhz; r1[4] = vlx; r1[5] = vly; r1[6] = vlz; r1[7] = (__bf16)0.f;
    *(bf16x8*)(posb + tid * PB_STRIDE) = r0;
    *(bf16x8*)(posb + tid * PB_STRIDE + 8) = r1;
  }
  __syncthreads();

  // ---- layer 0: h0 = relu(pos @ w0 + b0) via fixup-MFMA (error-compensated) ----
  {
    f32x4 acc[8][2];
    int nbase = wv * 32;
    f32x4 bia0 = *(const f32x4*)(b0 + nbase + quad * 4);
    f32x4 bia1 = *(const f32x4*)(b0 + nbase + 16 + quad * 4);
#pragma unroll
    for (int pt = 0; pt < 8; ++pt) { acc[pt][0] = bia0; acc[pt][1] = bia1; }
    gemmFix<2>(posb, ws + W0E, acc, nbase, l16, quad);
#pragma unroll
    for (int nt = 0; nt < 2; ++nt) {
      int nc = nbase + nt * 16 + quad * 4;
#pragma unroll
      for (int pt = 0; pt < 8; ++pt)
        store_relu(acc[pt][nt], act + (pt * 16 + l16) * STRIDE + nc);
    }
    __syncthreads();
  }

  // ---- layer 1 ----
  {
    f32x4 acc[8][2];
    int nbase = wv * 32;
    f32x4 bia0 = *(const f32x4*)(b1 + nbase + quad * 4);
    f32x4 bia1 = *(const f32x4*)(b1 + nbase + 16 + quad * 4);
#pragma unroll
    for (int pt = 0; pt < 8; ++pt) { acc[pt][0] = bia0; acc[pt][1] = bia1; }
    gemmW<2>(act, ws + W1T, acc, nbase, l16, quad);
    __syncthreads();
#pragma unroll
    for (int nt = 0; nt < 2; ++nt) {
      int nc = nbase + nt * 16 + quad * 4;
#pragma unroll
      for (int pt = 0; pt < 8; ++pt)
        store_relu(acc[pt][nt], act + (pt * 16 + l16) * STRIDE + nc);
    }
    __syncthreads();
  }

  // ---- layer 2: h2 = relu(h1 @ w2[:128] + pos @ w2[128:] + b2), concat via fixup-MFMA ----
  {
    f32x4 acc[8][2];
    int nbase = wv * 32;
    f32x4 bia0 = *(const f32x4*)(b2 + nbase + quad * 4);
    f32x4 bia1 = *(const f32x4*)(b2 + nbase + 16 + quad * 4);
#pragma unroll
    for (int pt = 0; pt < 8; ++pt) { acc[pt][0] = bia0; acc[pt][1] = bia1; }
    gemmW<2>(act, ws + W2T, acc, nbase, l16, quad);
    gemmFix<2>(posb, ws + W2E, acc, nbase, l16, quad);
    __syncthreads();
#pragma unroll
    for (int nt = 0; nt < 2; ++nt) {
      int nc = nbase + nt * 16 + quad * 4;
#pragma unroll
      for (int pt = 0; pt < 8; ++pt)
        store_relu(acc[pt][nt], act + (pt * 16 + l16) * STRIDE + nc);
    }
    __syncthreads();
  }

  // ---- layer 3 ----
  {
    f32x4 acc[8][2];
    int nbase = wv * 32;
    f32x4 bia0 = *(const f32x4*)(b3 + nbase + quad * 4);
    f32x4 bia1 = *(const f32x4*)(b3 + nbase + 16 + quad * 4);
#pragma unroll
    for (int pt = 0; pt < 8; ++pt) { acc[pt][0] = bia0; acc[pt][1] = bia1; }
    gemmW<2>(act, ws + W3T, acc, nbase, l16, quad);
    __syncthreads();
#pragma unroll
    for (int nt = 0; nt < 2; ++nt) {
      int nc = nbase + nt * 16 + quad * 4;
#pragma unroll
      for (int pt = 0; pt < 8; ++pt)
        store_relu(acc[pt][nt], act + (pt * 16 + l16) * STRIDE + nc);
    }
    __syncthreads();
  }

  // ---- density = relu(h3 @ wd + bd) (reads act only; next gemm also only reads) ----
  {
    int p = tid >> 1, half = tid & 1;
    const __bf16* hrow = act + p * STRIDE + half * 64;
    const float*  wdp  = wd + half * 64;
    float s = 0.f;
#pragma unroll
    for (int c = 0; c < 8; ++c) {
      bf16x8 h = *(const bf16x8*)(hrow + c * 8);
      f32x4 wa = *(const f32x4*)(wdp + c * 8);
      f32x4 wb = *(const f32x4*)(wdp + c * 8 + 4);
      s += (float)h[0] * wa[0] + (float)h[1] * wa[1] + (float)h[2] * wa[2] + (float)h[3] * wa[3];
      s += (float)h[4] * wb[0] + (float)h[5] * wb[1] + (float)h[6] * wb[2] + (float)h[7] * wb[3];
    }
    s += __shfl_xor(s, 1, 64);
    if (half == 0) out[(size_t)3 * N_PTS + p0 + p] = fmaxf(s + bd[0], 0.f);
  }

  // ---- features = relu(h3 @ wf + bf) ----
  {
    f32x4 acc[8][2];
    int nbase = wv * 32;
    f32x4 bia0 = *(const f32x4*)(bfv + nbase + quad * 4);
    f32x4 bia1 = *(const f32x4*)(bfv + nbase + 16 + quad * 4);
#pragma unroll
    for (int pt = 0; pt < 8; ++pt) { acc[pt][0] = bia0; acc[pt][1] = bia1; }
    gemmW<2>(act, ws + WFT, acc, nbase, l16, quad);
    __syncthreads();
#pragma unroll
    for (int nt = 0; nt < 2; ++nt) {
      int nc = nbase + nt * 16 + quad * 4;
#pragma unroll
      for (int pt = 0; pt < 8; ++pt)
        store_relu(acc[pt][nt], act + (pt * 16 + l16) * STRIDE + nc);
    }
    __syncthreads();
  }

  // ---- r = relu([features, vdir] @ wr + br), N=64, vdir via fixup-MFMA ----
  {
    f32x4 acc[8][1];
    int nbase = wv * 16;
    f32x4 bia0 = *(const f32x4*)(br + nbase + quad * 4);
#pragma unroll
    for (int pt = 0; pt < 8; ++pt) acc[pt][0] = bia0;
    gemmW<1>(act, ws + WRT, acc, nbase, l16, quad);
    gemmFix<1>(posb, ws + WRE, acc, nbase, l16, quad);
    __syncthreads();
    int nc = nbase + quad * 4;
#pragma unroll
    for (int pt = 0; pt < 8; ++pt)
      store_relu(acc[pt][0], act + (pt * 16 + l16) * STRIDE + nc);
    __syncthreads();
  }

  // ---- rgb = sigmoid(r @ wo + bo), woT fp32 from ws ----
  {
    const float* woT = (const float*)(ws + WSF);  // [3][64]
    int p = tid >> 1, half = tid & 1;
    const __bf16* rrow = act + p * STRIDE + half * 32;
    float s0 = 0.f, s1 = 0.f, s2 = 0.f;
#pragma unroll
    for (int c = 0; c < 4; ++c) {
      bf16x8 h = *(const bf16x8*)(rrow + c * 8);
#pragma unroll
      for (int j = 0; j < 8; ++j) {
        int kg = half * 32 + c * 8 + j;
        float rv = (float)h[j];
        s0 += rv * woT[kg];
        s1 += rv * woT[64 + kg];
        s2 += rv * woT[128 + kg];
      }
    }
    s0 += __shfl_xor(s0, 1, 64);
    s1 += __shfl_xor(s1, 1, 64);
    s2 += __shfl_xor(s2, 1, 64);
    if (half == 0) {
      size_t o = (size_t)(p0 + p) * 3;
      out[o + 0] = 1.f / (1.f + __expf(-(s0 + bo[0])));
      out[o + 1] = 1.f / (1.f + __expf(-(s1 + bo[1])));
      out[o + 2] = 1.f / (1.f + __expf(-(s2 + bo[2])));
    }
  }
}

extern "C" void kernel_launch(void* const* d_in, const int* in_sizes, int n_in,
                              void* d_out, int out_size, void* d_ws, size_t ws_size,
                              hipStream_t stream) {
  const float* x  = (const float*)d_in[0];
  const float* w0 = (const float*)d_in[1];
  const float* b0 = (const float*)d_in[2];
  const float* w1 = (const float*)d_in[3];
  const float* b1 = (const float*)d_in[4];
  const float* w2 = (const float*)d_in[5];
  const float* b2 = (const float*)d_in[6];
  const float* w3 = (const float*)d_in[7];
  const float* b3 = (const float*)d_in[8];
  const float* wd = (const float*)d_in[9];
  const float* bd = (const float*)d_in[10];
  const float* wf = (const float*)d_in[11];
  const float* bfv= (const float*)d_in[12];
  const float* wr = (const float*)d_in[13];
  const float* br = (const float*)d_in[14];
  const float* wo = (const float*)d_in[15];
  const float* bo = (const float*)d_in[16];
  __bf16* ws = (__bf16*)d_ws;
  float* out = (float*)d_out;

  prep_kernel<<<309, 256, 0, stream>>>(w0, w1, w2, w3, wf, wr, wo, ws);
  nerf_kernel<<<N_PTS / TM, 256, 0, stream>>>(x, b0, b1, b2, b3, wd, bd, bfv, br, bo, ws, out);
}